// Round 11
// baseline (385.362 us; speedup 1.0000x reference)
//
#include <hip/hip_runtime.h>
#include <stdint.h>

// Problem dims (fixed): B=4, S=2048, IN=1024, OUT=4096 -> M=8192, K=1024, N=4096
#define M_DIM 8192
#define K_DIM 1024
#define N_DIM 4096

typedef int int32x4 __attribute__((ext_vector_type(4)));

// round-to-nearest-even quantize 4 floats -> packed i8x4
__device__ __forceinline__ uint32_t pack4(float a, float b, float c, float d, float inv) {
  int q0 = (int)rintf(a * inv), q1 = (int)rintf(b * inv),
      q2 = (int)rintf(c * inv), q3 = (int)rintf(d * inv);
  q0 = q0 > 127 ? 127 : (q0 < -127 ? -127 : q0);
  q1 = q1 > 127 ? 127 : (q1 < -127 ? -127 : q1);
  q2 = q2 > 127 ? 127 : (q2 < -127 ? -127 : q2);
  q3 = q3 > 127 ? 127 : (q3 < -127 ? -127 : q3);
  return (uint32_t)(q0 & 255) | ((uint32_t)(q1 & 255) << 8) |
         ((uint32_t)(q2 & 255) << 16) | ((uint32_t)(q3 & 255) << 24);
}

// ---------------- kernel 1: quantize A rows fp32 -> i8 + per-row scale ----------------
__global__ __launch_bounds__(256) void quant_a_kernel(
    const float* __restrict__ input,   // (8192, 1024) fp32
    int8_t*      __restrict__ a8,      // (8192, 1024) i8
    float*       __restrict__ sA)      // (8192) row scales
{
  const int wave = threadIdx.x >> 6, lane = threadIdx.x & 63;
  const int row  = blockIdx.x * 4 + wave;
  const float* rp = input + (size_t)row * K_DIM;

  float4 v[4];
  float m = 0.f;
#pragma unroll
  for (int j = 0; j < 4; j++) {
    v[j] = ((const float4*)rp)[j * 64 + lane];
    m = fmaxf(m, fmaxf(fmaxf(fabsf(v[j].x), fabsf(v[j].y)),
                       fmaxf(fabsf(v[j].z), fabsf(v[j].w))));
  }
#pragma unroll
  for (int off = 32; off >= 1; off >>= 1) m = fmaxf(m, __shfl_xor(m, off));

  const float inv = (m > 0.f) ? 127.f / m : 0.f;
  uint32_t* op = (uint32_t*)(a8 + (size_t)row * K_DIM);
#pragma unroll
  for (int j = 0; j < 4; j++)
    op[j * 64 + lane] = pack4(v[j].x, v[j].y, v[j].z, v[j].w, inv);
  if (lane == 0) sA[row] = m * (1.f / 127.f);
}

// ---------------- kernel 2: fold everything into W5^T, quantize rows to i8 ----------------
__global__ __launch_bounds__(256) void build_w_kernel(
    const float* __restrict__ weight,      // (4096, 1024)
    const float* __restrict__ mask,        // (4096, 1024)
    const float* __restrict__ in_scores,   // (512)
    const float* __restrict__ out_scores,  // (2048)
    const int*   __restrict__ in_mapping,  // (1024)
    const int*   __restrict__ out_mapping, // (4096)
    int8_t*      __restrict__ w8,          // (4096, 1024) i8: row=o, col=i
    float*       __restrict__ sW)          // (4096) row scales
{
  __shared__ float w0[K_DIM], w1[K_DIM];
  __shared__ float o0f[K_DIM], o1f[K_DIM];
  __shared__ float red[8];

  const int mo = blockIdx.x;       // out-pair [0, 2048)
  const int t  = threadIdx.x;      // [0, 256)

  const int r0 = out_mapping[2 * mo];
  const int r1 = out_mapping[2 * mo + 1];

  ((float4*)w0)[t] = ((const float4*)(weight + (size_t)r0 * K_DIM))[t];
  ((float4*)w1)[t] = ((const float4*)(weight + (size_t)r1 * K_DIM))[t];

  const float ao = out_scores[mo];
  const float so = sinf(ao), co = cosf(ao);

  __syncthreads();

#pragma unroll
  for (int s = 0; s < 2; s++) {
    const int mi = t + s * 256;
    const float ai = in_scores[mi];
    const float si = sinf(ai), ci = cosf(ai);
    const int ia0 = in_mapping[2 * mi];
    const int ia1 = in_mapping[2 * mi + 1];

    const float w00 = w0[ia0], w01 = w0[ia1];
    const float w10 = w1[ia0], w11 = w1[ia1];

    float a00 =  ci * w00 + si * w01;
    float a01 = -si * w00 + ci * w01;
    float a10 =  ci * w10 + si * w11;
    float a11 = -si * w10 + ci * w11;

    float b00 = co * a00 - so * a10;
    float b10 = co * a01 - so * a11;
    float b01 = so * a00 + co * a10;
    float b11 = so * a01 + co * a11;

    const float2 mk0 = *(const float2*)&mask[(size_t)(2 * mo) * K_DIM + 2 * mi];
    const float2 mk1 = *(const float2*)&mask[(size_t)(2 * mo + 1) * K_DIM + 2 * mi];
    b00 *= mk0.x; b10 *= mk0.y;
    b01 *= mk1.x; b11 *= mk1.y;

    float c00 =  co * b00 + so * b01;
    float c10 =  co * b10 + so * b11;
    float c01 = -so * b00 + co * b01;
    float c11 = -so * b10 + co * b11;

    o0f[ia0] = ci * c00 - si * c10;
    o0f[ia1] = si * c00 + ci * c10;
    o1f[ia0] = ci * c01 - si * c11;
    o1f[ia1] = si * c01 + ci * c11;
  }

  __syncthreads();

  float m0 = 0.f, m1 = 0.f;
#pragma unroll
  for (int e = 0; e < 4; e++) {
    m0 = fmaxf(m0, fabsf(o0f[4 * t + e]));
    m1 = fmaxf(m1, fabsf(o1f[4 * t + e]));
  }
#pragma unroll
  for (int off = 32; off >= 1; off >>= 1) {
    m0 = fmaxf(m0, __shfl_xor(m0, off));
    m1 = fmaxf(m1, __shfl_xor(m1, off));
  }
  if ((t & 63) == 0) { red[(t >> 6) * 2] = m0; red[(t >> 6) * 2 + 1] = m1; }
  __syncthreads();
  m0 = fmaxf(fmaxf(red[0], red[2]), fmaxf(red[4], red[6]));
  m1 = fmaxf(fmaxf(red[1], red[3]), fmaxf(red[5], red[7]));

  const float inv0 = (m0 > 0.f) ? 127.f / m0 : 0.f;
  const float inv1 = (m1 > 0.f) ? 127.f / m1 : 0.f;

  ((uint32_t*)(w8 + (size_t)r0 * K_DIM))[t] =
      pack4(o0f[4 * t], o0f[4 * t + 1], o0f[4 * t + 2], o0f[4 * t + 3], inv0);
  ((uint32_t*)(w8 + (size_t)r1 * K_DIM))[t] =
      pack4(o1f[4 * t], o1f[4 * t + 1], o1f[4 * t + 2], o1f[4 * t + 3], inv1);
  if (t == 0) { sW[r0] = m0 * (1.f / 127.f); sW[r1] = m1 * (1.f / 127.f); }
}

// ---------------- kernel 3: i8 GEMM, C = dequant(A8 * W8^T) ----------------
// R15 = R12 VERBATIM (best: 227.9 us, absmax 0.0352; 2-slot 48 KB LDS, two
// barriers/tile, counted vmcnt(6)) with exactly ONE change:
// __launch_bounds__(256, 3) -- request 3 waves/EU (= 3 blocks/CU of 4 waves).
// Static limits allow it (LDS floor(160/48)=3; VGPR 112 <= 512/3=170), but
// measured OccupancyPercent ~19.5% indicated only ~2 resident blocks under
// the (256,2) declaration. A 3rd co-resident block supplies MFMA work during
// the other blocks' barrier-aligned LDS/drain windows -> pushes toward the
// ~20 us LDS-pipe bound. R13's nt-stores/prefetch-in-cluster stay reverted;
// R14's 3-slot (72 KB) is incompatible with 3 blocks/CU, and measured == R12.
__device__ __forceinline__ void async_load16(const int8_t* g, int8_t* lds_wave_uniform) {
  __builtin_amdgcn_global_load_lds(
      (const __attribute__((address_space(1))) uint32_t*)g,
      (__attribute__((address_space(3))) uint32_t*)lds_wave_uniform,
      16, 0, 0);
}

__global__ __launch_bounds__(256, 3) void gemm_kernel(
    const int8_t* __restrict__ A,    // (8192, 1024) i8
    const int8_t* __restrict__ BT,   // (4096, 1024) i8 (W5^T, row=n, col=k)
    const float*  __restrict__ sA,   // (8192)
    const float*  __restrict__ sW,   // (4096)
    float* __restrict__ C)           // (8192, 4096) fp32
{
  __shared__ __align__(16) int8_t As[2][256 * 64];  // 2 x 16 KB
  __shared__ __align__(16) int8_t Bs[2][128 * 64];  // 2 x  8 KB

  const int tid  = threadIdx.x;     // 0..255
  const int w    = tid >> 6;        // wave 0..3
  const int lane = tid & 63;
  const int quad = lane >> 4;       // k-chunk of the fragment (k = quad*16..+15)
  const int rr   = lane & 15;
  const int wm2  = w >> 1;          // 0..1 (M half: 128 rows)
  const int wn2  = w & 1;           // 0..1 (N half: 64 cols)

  // XCD-chunked bijective swizzle: 1024 blocks, 128 per XCD, bn fastest.
  const int flat = blockIdx.x;                       // 0..1023
  const int swz  = ((flat & 7) << 7) | (flat >> 3);
  const int bm   = swz >> 5;        // 0..31  (M tile of 256)
  const int bn   = swz & 31;        // 0..31  (N tile of 128)

  int32x4 acc[8][4] = {};

  // ---- staging source pointers (per-lane, XOR-preswizzled, rule 21) ----
  const int8_t* gA[4];
  const int8_t* gB[2];
#pragma unroll
  for (int ii = 0; ii < 4; ii++) {
    const int c   = ii * 256 + tid;
    const int row = c >> 2;                     // 0..255
    const int g   = (c & 3) ^ ((row >> 1) & 3);
    gA[ii] = A + (size_t)(bm * 256 + row) * K_DIM + g * 16;
  }
#pragma unroll
  for (int ii = 0; ii < 2; ii++) {
    const int c   = ii * 256 + tid;
    const int row = c >> 2;                     // 0..127
    const int g   = (c & 3) ^ ((row >> 1) & 3);
    gB[ii] = BT + (size_t)(bn * 128 + row) * K_DIM + g * 16;
  }

#define STAGE(BUF, KT)                                                        \
  do {                                                                        \
    _Pragma("unroll")                                                         \
    for (int ii_ = 0; ii_ < 4; ii_++)                                         \
      async_load16(gA[ii_] + (KT) * 64, &As[BUF][(ii_ * 256 + w * 64) * 16]); \
    _Pragma("unroll")                                                         \
    for (int ii_ = 0; ii_ < 2; ii_++)                                         \
      async_load16(gB[ii_] + (KT) * 64, &Bs[BUF][(ii_ * 256 + w * 64) * 16]); \
  } while (0)

  // ---- fragment LDS byte offsets (swizzle matches staging) ----
  int offA[8], offB[4];
#pragma unroll
  for (int i = 0; i < 8; i++) {
    const int r = wm2 * 128 + i * 16 + rr;
    offA[i] = r * 64 + (quad ^ ((r >> 1) & 3)) * 16;
  }
#pragma unroll
  for (int j = 0; j < 4; j++) {
    const int r = wn2 * 64 + j * 16 + rr;
    offB[j] = r * 64 + (quad ^ ((r >> 1) & 3)) * 16;
  }

  // MODE: 0 steady (t<=13), 1 = t14 (no stage, vmcnt(0)), 2 = t15 (drain)
#define TILE(T, MODE)                                                         \
  {                                                                           \
    const int buf_ = (T) & 1;                                                 \
    const int8_t* asb_ = &As[buf_][0];                                        \
    const int8_t* bsb_ = &Bs[buf_][0];                                        \
    int32x4 af[8], bf[4];                                                     \
    _Pragma("unroll") for (int i_ = 0; i_ < 8; i_++)                          \
      af[i_] = *reinterpret_cast<const int32x4*>(asb_ + offA[i_]);            \
    _Pragma("unroll") for (int j_ = 0; j_ < 4; j_++)                          \
      bf[j_] = *reinterpret_cast<const int32x4*>(bsb_ + offB[j_]);            \
    asm volatile("s_waitcnt lgkmcnt(0)" ::: "memory");                        \
    __builtin_amdgcn_sched_barrier(0);  /* rule 18 */                         \
    __builtin_amdgcn_s_barrier();       /* all waves' reads done (WAR) */     \
    if (MODE == 0) STAGE(buf_, (T) + 2);                                      \
    __builtin_amdgcn_s_setprio(1);                                            \
    _Pragma("unroll") for (int i_ = 0; i_ < 8; i_++)                          \
      _Pragma("unroll") for (int j_ = 0; j_ < 4; j_++)                        \
        acc[i_][j_] = __builtin_amdgcn_mfma_i32_16x16x64_i8(                  \
            af[i_], bf[j_], acc[i_][j_], 0, 0, 0);                            \
    __builtin_amdgcn_s_setprio(0);                                            \
    if (MODE == 0)      { asm volatile("s_waitcnt vmcnt(6)" ::: "memory"); }  \
    else if (MODE == 1) { asm volatile("s_waitcnt vmcnt(0)" ::: "memory"); }  \
    if (MODE < 2) __builtin_amdgcn_s_barrier();                               \
  }

  // ---- prologue: stage tiles 0,1; wait tile 0 (leave tile 1 in flight) ----
  STAGE(0, 0);
  STAGE(1, 1);
  asm volatile("s_waitcnt vmcnt(6)" ::: "memory");
  __builtin_amdgcn_s_barrier();

  // ---- main loop: 16 K-tiles (K=64 each) ----
  for (int t = 0; t < 14; ++t) {
    TILE(t, 0);
  }
  TILE(14, 1);
  TILE(15, 2);

#undef TILE
#undef STAGE

  // ---- epilogue: D layout col = lane&15 (n), row = quad*4 + reg (m);
  // dequant C = (float)acc * sA[row] * sW[col] ----
  float sw4[4];
#pragma unroll
  for (int j = 0; j < 4; j++)
    sw4[j] = sW[bn * 128 + wn2 * 64 + j * 16 + rr];

#pragma unroll
  for (int i = 0; i < 8; i++) {
    const int row0 = bm * 256 + wm2 * 128 + i * 16 + quad * 4;
#pragma unroll
    for (int rg = 0; rg < 4; rg++) {
      const float sa = sA[row0 + rg];
#pragma unroll
      for (int j = 0; j < 4; j++) {
        const int col = bn * 128 + wn2 * 64 + j * 16 + rr;
        C[(size_t)(row0 + rg) * N_DIM + col] = (float)acc[i][j][rg] * sa * sw4[j];
      }
    }
  }
}

extern "C" void kernel_launch(void* const* d_in, const int* in_sizes, int n_in,
                              void* d_out, int out_size, void* d_ws, size_t ws_size,
                              hipStream_t stream) {
  const float* input      = (const float*)d_in[0];
  const float* weight     = (const float*)d_in[1];
  const float* mask       = (const float*)d_in[2];
  const float* in_scores  = (const float*)d_in[3];
  const float* out_scores = (const float*)d_in[4];
  const int*   in_mapping = (const int*)d_in[5];
  const int*   out_mapping= (const int*)d_in[6];
  // d_in[7] = out_mapping_reverse (folded away), d_in[8] = temperature (unused)
  float* out = (float*)d_out;

  int8_t* a8 = (int8_t*)d_ws;                                        //  8 MB
  int8_t* w8 = (int8_t*)d_ws + (size_t)M_DIM * K_DIM;                //  4 MB
  float*  sA = (float*)((char*)d_ws + 12 * 1024 * 1024);             // 32 KB
  float*  sW = (float*)((char*)d_ws + 12 * 1024 * 1024 + 32 * 1024); // 16 KB

  quant_a_kernel<<<2048, 256, 0, stream>>>(input, a8, sA);

  build_w_kernel<<<2048, 256, 0, stream>>>(
      weight, mask, in_scores, out_scores, in_mapping, out_mapping, w8, sW);

  gemm_kernel<<<1024, 256, 0, stream>>>(a8, w8, sA, sW, out);
}

// Round 12
// 222.764 us; speedup vs baseline: 1.7299x; 1.7299x over previous
//
#include <hip/hip_runtime.h>
#include <stdint.h>

// Problem dims (fixed): B=4, S=2048, IN=1024, OUT=4096 -> M=8192, K=1024, N=4096
#define M_DIM 8192
#define K_DIM 1024
#define N_DIM 4096

typedef int int32x4 __attribute__((ext_vector_type(4)));

// round-to-nearest-even quantize 4 floats -> packed i8x4
__device__ __forceinline__ uint32_t pack4(float a, float b, float c, float d, float inv) {
  int q0 = (int)rintf(a * inv), q1 = (int)rintf(b * inv),
      q2 = (int)rintf(c * inv), q3 = (int)rintf(d * inv);
  q0 = q0 > 127 ? 127 : (q0 < -127 ? -127 : q0);
  q1 = q1 > 127 ? 127 : (q1 < -127 ? -127 : q1);
  q2 = q2 > 127 ? 127 : (q2 < -127 ? -127 : q2);
  q3 = q3 > 127 ? 127 : (q3 < -127 ? -127 : q3);
  return (uint32_t)(q0 & 255) | ((uint32_t)(q1 & 255) << 8) |
         ((uint32_t)(q2 & 255) << 16) | ((uint32_t)(q3 & 255) << 24);
}

// ---------------- kernel 1: fused prologue ----------------
// blocks [0, 2048): fold everything into W5^T + quantize rows to i8
//                   (fp32 math chain verified through R12/R14, absmax 0.0352)
// blocks [2048, 4096): quantize A rows fp32 -> i8 + per-row scale
// Independent work; fusion pattern validated in R10 (branch on blockIdx).
__global__ __launch_bounds__(256) void prologue_kernel(
    const float* __restrict__ input,       // (8192, 1024) fp32
    const float* __restrict__ weight,      // (4096, 1024)
    const float* __restrict__ mask,        // (4096, 1024)
    const float* __restrict__ in_scores,   // (512)
    const float* __restrict__ out_scores,  // (2048)
    const int*   __restrict__ in_mapping,  // (1024)
    const int*   __restrict__ out_mapping, // (4096)
    int8_t*      __restrict__ a8,          // (8192, 1024) i8
    float*       __restrict__ sA,          // (8192) A row scales
    int8_t*      __restrict__ w8,          // (4096, 1024) i8: row=o, col=i
    float*       __restrict__ sW)          // (4096) W row scales
{
  __shared__ float w0[K_DIM], w1[K_DIM];
  __shared__ float o0f[K_DIM], o1f[K_DIM];
  __shared__ float red[8];

  const int bid = blockIdx.x;
  const int t   = threadIdx.x;

  if (bid >= 2048) {
    // ---- quant_a part: 4 rows per block, one wave per row ----
    const int wave = t >> 6, lane = t & 63;
    const int row  = (bid - 2048) * 4 + wave;       // < 8192 exactly
    const float* rp = input + (size_t)row * K_DIM;

    float4 v[4];
    float m = 0.f;
#pragma unroll
    for (int j = 0; j < 4; j++) {
      v[j] = ((const float4*)rp)[j * 64 + lane];
      m = fmaxf(m, fmaxf(fmaxf(fabsf(v[j].x), fabsf(v[j].y)),
                         fmaxf(fabsf(v[j].z), fabsf(v[j].w))));
    }
#pragma unroll
    for (int off = 32; off >= 1; off >>= 1) m = fmaxf(m, __shfl_xor(m, off));

    const float inv = (m > 0.f) ? 127.f / m : 0.f;
    uint32_t* op = (uint32_t*)(a8 + (size_t)row * K_DIM);
#pragma unroll
    for (int j = 0; j < 4; j++)
      op[j * 64 + lane] = pack4(v[j].x, v[j].y, v[j].z, v[j].w, inv);
    if (lane == 0) sA[row] = m * (1.f / 127.f);
    return;
  }

  // ---- build_w part (unchanged verified math) ----
  const int mo = bid;              // out-pair [0, 2048)

  const int r0 = out_mapping[2 * mo];
  const int r1 = out_mapping[2 * mo + 1];

  ((float4*)w0)[t] = ((const float4*)(weight + (size_t)r0 * K_DIM))[t];
  ((float4*)w1)[t] = ((const float4*)(weight + (size_t)r1 * K_DIM))[t];

  const float ao = out_scores[mo];
  const float so = sinf(ao), co = cosf(ao);

  __syncthreads();

#pragma unroll
  for (int s = 0; s < 2; s++) {
    const int mi = t + s * 256;
    const float ai = in_scores[mi];
    const float si = sinf(ai), ci = cosf(ai);
    const int ia0 = in_mapping[2 * mi];
    const int ia1 = in_mapping[2 * mi + 1];

    const float w00 = w0[ia0], w01 = w0[ia1];
    const float w10 = w1[ia0], w11 = w1[ia1];

    float a00 =  ci * w00 + si * w01;
    float a01 = -si * w00 + ci * w01;
    float a10 =  ci * w10 + si * w11;
    float a11 = -si * w10 + ci * w11;

    float b00 = co * a00 - so * a10;
    float b10 = co * a01 - so * a11;
    float b01 = so * a00 + co * a10;
    float b11 = so * a01 + co * a11;

    const float2 mk0 = *(const float2*)&mask[(size_t)(2 * mo) * K_DIM + 2 * mi];
    const float2 mk1 = *(const float2*)&mask[(size_t)(2 * mo + 1) * K_DIM + 2 * mi];
    b00 *= mk0.x; b10 *= mk0.y;
    b01 *= mk1.x; b11 *= mk1.y;

    float c00 =  co * b00 + so * b01;
    float c10 =  co * b10 + so * b11;
    float c01 = -so * b00 + co * b01;
    float c11 = -so * b10 + co * b11;

    o0f[ia0] = ci * c00 - si * c10;
    o0f[ia1] = si * c00 + ci * c10;
    o1f[ia0] = ci * c01 - si * c11;
    o1f[ia1] = si * c01 + ci * c11;
  }

  __syncthreads();

  float m0 = 0.f, m1 = 0.f;
#pragma unroll
  for (int e = 0; e < 4; e++) {
    m0 = fmaxf(m0, fabsf(o0f[4 * t + e]));
    m1 = fmaxf(m1, fabsf(o1f[4 * t + e]));
  }
#pragma unroll
  for (int off = 32; off >= 1; off >>= 1) {
    m0 = fmaxf(m0, __shfl_xor(m0, off));
    m1 = fmaxf(m1, __shfl_xor(m1, off));
  }
  if ((t & 63) == 0) { red[(t >> 6) * 2] = m0; red[(t >> 6) * 2 + 1] = m1; }
  __syncthreads();
  m0 = fmaxf(fmaxf(red[0], red[2]), fmaxf(red[4], red[6]));
  m1 = fmaxf(fmaxf(red[1], red[3]), fmaxf(red[5], red[7]));

  const float inv0 = (m0 > 0.f) ? 127.f / m0 : 0.f;
  const float inv1 = (m1 > 0.f) ? 127.f / m1 : 0.f;

  ((uint32_t*)(w8 + (size_t)r0 * K_DIM))[t] =
      pack4(o0f[4 * t], o0f[4 * t + 1], o0f[4 * t + 2], o0f[4 * t + 3], inv0);
  ((uint32_t*)(w8 + (size_t)r1 * K_DIM))[t] =
      pack4(o1f[4 * t], o1f[4 * t + 1], o1f[4 * t + 2], o1f[4 * t + 3], inv1);
  if (t == 0) { sW[r0] = m0 * (1.f / 127.f); sW[r1] = m1 * (1.f / 127.f); }
}

// ---------------- kernel 2: i8 GEMM, C = dequant(A8 * W8^T) ----------------
// R16 = R14 VERBATIM (best measured: 227.1 us, absmax 0.0352).
// 3-slot circular LDS, one barrier per K-tile, counted vmcnt(6), XOR
// pre-swizzle (0 conflicts), __launch_bounds__(256, 2).
// R15's (256,3) is REVERTED: it capped VGPR 112->84, spilled the 128-VGPR
// accumulator to scratch (WRITE_SIZE 131->577 MB, MfmaUtil 5%, gemm 265 us).
//   iter t: STAGE(t+2 -> slot (t+2)%3)   [slot == (t-1)%3, WAR-safe]
//           12 ds_read frags from slot t%3 [certified at barrier(t-1)]
//           lgkm0 ; sched_barrier ; vmcnt(6) [stage(t+1) landed, t+2 flying]
//           s_barrier  [WAR slot t%3 + RAW slot (t+1)%3, block-wide]
//           32 MFMA.
//   Tails: t=14 no stage + vmcnt(0); t=15 reads+lgkm0+MFMA only.
__device__ __forceinline__ void async_load16(const int8_t* g, int8_t* lds_wave_uniform) {
  __builtin_amdgcn_global_load_lds(
      (const __attribute__((address_space(1))) uint32_t*)g,
      (__attribute__((address_space(3))) uint32_t*)lds_wave_uniform,
      16, 0, 0);
}

__global__ __launch_bounds__(256, 2) void gemm_kernel(
    const int8_t* __restrict__ A,    // (8192, 1024) i8
    const int8_t* __restrict__ BT,   // (4096, 1024) i8 (W5^T, row=n, col=k)
    const float*  __restrict__ sA,   // (8192)
    const float*  __restrict__ sW,   // (4096)
    float* __restrict__ C)           // (8192, 4096) fp32
{
  __shared__ __align__(16) int8_t As[3][256 * 64];  // 3 x 16 KB
  __shared__ __align__(16) int8_t Bs[3][128 * 64];  // 3 x  8 KB

  const int tid  = threadIdx.x;     // 0..255
  const int w    = tid >> 6;        // wave 0..3
  const int lane = tid & 63;
  const int quad = lane >> 4;       // k-chunk of the fragment (k = quad*16..+15)
  const int rr   = lane & 15;
  const int wm2  = w >> 1;          // 0..1 (M half: 128 rows)
  const int wn2  = w & 1;           // 0..1 (N half: 64 cols)

  // XCD-chunked bijective swizzle: 1024 blocks, 128 per XCD, bn fastest.
  const int flat = blockIdx.x;                       // 0..1023
  const int swz  = ((flat & 7) << 7) | (flat >> 3);
  const int bm   = swz >> 5;        // 0..31  (M tile of 256)
  const int bn   = swz & 31;        // 0..31  (N tile of 128)

  int32x4 acc[8][4] = {};

  // ---- staging source pointers (per-lane, XOR-preswizzled, rule 21) ----
  const int8_t* gA[4];
  const int8_t* gB[2];
#pragma unroll
  for (int ii = 0; ii < 4; ii++) {
    const int c   = ii * 256 + tid;
    const int row = c >> 2;                     // 0..255
    const int g   = (c & 3) ^ ((row >> 1) & 3);
    gA[ii] = A + (size_t)(bm * 256 + row) * K_DIM + g * 16;
  }
#pragma unroll
  for (int ii = 0; ii < 2; ii++) {
    const int c   = ii * 256 + tid;
    const int row = c >> 2;                     // 0..127
    const int g   = (c & 3) ^ ((row >> 1) & 3);
    gB[ii] = BT + (size_t)(bn * 128 + row) * K_DIM + g * 16;
  }

#define STAGE(SLOT, KT)                                                        \
  do {                                                                         \
    _Pragma("unroll")                                                          \
    for (int ii_ = 0; ii_ < 4; ii_++)                                          \
      async_load16(gA[ii_] + (KT) * 64, &As[SLOT][(ii_ * 256 + w * 64) * 16]); \
    _Pragma("unroll")                                                          \
    for (int ii_ = 0; ii_ < 2; ii_++)                                          \
      async_load16(gB[ii_] + (KT) * 64, &Bs[SLOT][(ii_ * 256 + w * 64) * 16]); \
  } while (0)

  // ---- fragment LDS byte offsets (swizzle matches staging) ----
  int offA[8], offB[4];
#pragma unroll
  for (int i = 0; i < 8; i++) {
    const int r = wm2 * 128 + i * 16 + rr;
    offA[i] = r * 64 + (quad ^ ((r >> 1) & 3)) * 16;
  }
#pragma unroll
  for (int j = 0; j < 4; j++) {
    const int r = wn2 * 64 + j * 16 + rr;
    offB[j] = r * 64 + (quad ^ ((r >> 1) & 3)) * 16;
  }

  // MODE: 0 steady (t<=13), 1 = t14 (no stage, vmcnt(0)), 2 = t15 (drain)
#define TILE(T, SLOT, MODE)                                                   \
  {                                                                           \
    if (MODE == 0) STAGE(((SLOT) + 2) % 3, (T) + 2);                          \
    const int8_t* asb_ = &As[SLOT][0];                                        \
    const int8_t* bsb_ = &Bs[SLOT][0];                                        \
    int32x4 af[8], bf[4];                                                     \
    _Pragma("unroll") for (int i_ = 0; i_ < 8; i_++)                          \
      af[i_] = *reinterpret_cast<const int32x4*>(asb_ + offA[i_]);            \
    _Pragma("unroll") for (int j_ = 0; j_ < 4; j_++)                          \
      bf[j_] = *reinterpret_cast<const int32x4*>(bsb_ + offB[j_]);            \
    asm volatile("s_waitcnt lgkmcnt(0)" ::: "memory");                        \
    __builtin_amdgcn_sched_barrier(0);  /* rule 18 */                         \
    if (MODE == 0)      { asm volatile("s_waitcnt vmcnt(6)" ::: "memory"); }  \
    else if (MODE == 1) { asm volatile("s_waitcnt vmcnt(0)" ::: "memory"); }  \
    if (MODE < 2) __builtin_amdgcn_s_barrier();                               \
    __builtin_amdgcn_s_setprio(1);                                            \
    _Pragma("unroll") for (int i_ = 0; i_ < 8; i_++)                          \
      _Pragma("unroll") for (int j_ = 0; j_ < 4; j_++)                        \
        acc[i_][j_] = __builtin_amdgcn_mfma_i32_16x16x64_i8(                  \
            af[i_], bf[j_], acc[i_][j_], 0, 0, 0);                            \
    __builtin_amdgcn_s_setprio(0);                                            \
  }

  // ---- prologue: stage tiles 0,1 into slots 0,1; certify slot 0 ----
  STAGE(0, 0);
  STAGE(1, 1);
  asm volatile("s_waitcnt vmcnt(6)" ::: "memory");   // stage(0) landed
  __builtin_amdgcn_s_barrier();                      // slot 0 block-wide

  // ---- main loop: 16 K-tiles (K=64 each), slots unrolled mod 3 ----
  for (int t = 0; t < 12; t += 3) {
    TILE(t,     0, 0);
    TILE(t + 1, 1, 0);
    TILE(t + 2, 2, 0);
  }
  TILE(12, 0, 0);
  TILE(13, 1, 0);   // stages tile 15 -> slot 0
  TILE(14, 2, 1);
  TILE(15, 0, 2);

#undef TILE
#undef STAGE

  // ---- epilogue: D layout col = lane&15 (n), row = quad*4 + reg (m);
  // dequant C = (float)acc * sA[row] * sW[col] ----
  float sw4[4];
#pragma unroll
  for (int j = 0; j < 4; j++)
    sw4[j] = sW[bn * 128 + wn2 * 64 + j * 16 + rr];

#pragma unroll
  for (int i = 0; i < 8; i++) {
    const int row0 = bm * 256 + wm2 * 128 + i * 16 + quad * 4;
#pragma unroll
    for (int rg = 0; rg < 4; rg++) {
      const float sa = sA[row0 + rg];
#pragma unroll
      for (int j = 0; j < 4; j++) {
        const int col = bn * 128 + wn2 * 64 + j * 16 + rr;
        C[(size_t)(row0 + rg) * N_DIM + col] = (float)acc[i][j][rg] * sa * sw4[j];
      }
    }
  }
}

extern "C" void kernel_launch(void* const* d_in, const int* in_sizes, int n_in,
                              void* d_out, int out_size, void* d_ws, size_t ws_size,
                              hipStream_t stream) {
  const float* input      = (const float*)d_in[0];
  const float* weight     = (const float*)d_in[1];
  const float* mask       = (const float*)d_in[2];
  const float* in_scores  = (const float*)d_in[3];
  const float* out_scores = (const float*)d_in[4];
  const int*   in_mapping = (const int*)d_in[5];
  const int*   out_mapping= (const int*)d_in[6];
  // d_in[7] = out_mapping_reverse (folded away), d_in[8] = temperature (unused)
  float* out = (float*)d_out;

  int8_t* a8 = (int8_t*)d_ws;                                        //  8 MB
  int8_t* w8 = (int8_t*)d_ws + (size_t)M_DIM * K_DIM;                //  4 MB
  float*  sA = (float*)((char*)d_ws + 12 * 1024 * 1024);             // 32 KB
  float*  sW = (float*)((char*)d_ws + 12 * 1024 * 1024 + 32 * 1024); // 16 KB

  prologue_kernel<<<4096, 256, 0, stream>>>(
      input, weight, mask, in_scores, out_scores, in_mapping, out_mapping,
      a8, sA, w8, sW);

  gemm_kernel<<<1024, 256, 0, stream>>>(a8, w8, sA, sW, out);
}